// Round 1
// baseline (101.864 us; speedup 1.0000x reference)
//
#include <hip/hip_runtime.h>

#define B_TOTAL 524288
#define NBLK 2048
#define NTHR 256

// Per-channel MSE weights: VAR_IDX=[2,1,0,3,4], VAR_W=[0.5,0.15,0.15,0.1,0.1]
//   -> ch0:0.15 ch1:0.15 ch2:0.5 ch3:0.1 ch4:0.1
// step_w = (1/(s+1)) / (25/12) = [0.48, 0.24, 0.16, 0.12]

__global__ __launch_bounds__(NTHR) void loss_partial(
    const float* __restrict__ pred,    // (B,4,16)
    const float* __restrict__ target,  // (B,4,16)
    const float* __restrict__ inseq,   // (B,8,16)
    const float* __restrict__ scale,   // (16)
    const float* __restrict__ mean,    // (16)
    float* __restrict__ partials)      // (10, NBLK) SoA
{
    const int b = blockIdx.x * NTHR + threadIdx.x;

    // uniform scalars (compiler emits s_loads; broadcast, cached)
    const float sc0 = scale[0], sc2 = scale[2], sc3 = scale[3], sc4 = scale[4];
    const float sc5 = scale[5], sc7 = scale[7], sc8 = scale[8], sc9 = scale[9], sc11 = scale[11];
    const float mn3 = mean[3], mn4 = mean[4];

    const float stepw[4] = {0.48f, 0.24f, 0.16f, 0.12f};

    float acc_mse = 0.f, acc_rest = 0.f;
    float hbn0 = 0.f, hbn1 = 0.f, hbn2 = 0.f, hbn3 = 0.f;
    float hbd0 = 0.f, hbd1 = 0.f, hbd2 = 0.f, hbd3 = 0.f;

    {
        const float4* pr = reinterpret_cast<const float4*>(pred + (size_t)b * 64);
        const float4* tg = reinterpret_cast<const float4*>(target + (size_t)b * 64);
        // last window row: inseq[b, 7, 0..11] -> byte offset b*512 + 448, 16B aligned
        const float4* iq = reinterpret_cast<const float4*>(inseq + (size_t)b * 128 + 112);

        float4 q0 = iq[0], q1 = iq[1], q2 = iq[2];
        // prev channels needed: 0,2,5,7,8,9,11
        float pv0 = q0.x, pv2 = q0.z, pv5 = q1.y, pv7 = q1.w;
        float pv8 = q2.x, pv9 = q2.y, pv11 = q2.w;

#pragma unroll
        for (int s = 0; s < 4; ++s) {
            float4 p0 = pr[s * 4 + 0];          // ch 0-3
            float4 p1 = pr[s * 4 + 1];          // ch 4-7
            float4 p2 = pr[s * 4 + 2];          // ch 8-11
            float4 t0 = tg[s * 4 + 0];          // ch 0-3
            float4 t1 = tg[s * 4 + 1];          // ch 4-7
            const float sw = stepw[s];

            // ---- MSE (channels 0..4) ----
            float d0 = p0.x - t0.x, d1 = p0.y - t0.y, d2 = p0.z - t0.z;
            float d3 = p0.w - t0.w, d4 = p1.x - t1.x;
            acc_mse += sw * (0.15f * d0 * d0 + 0.15f * d1 * d1 + 0.5f * d2 * d2 +
                             0.1f * d3 * d3 + 0.1f * d4 * d4);

            // ---- heat balance: air = pd ch3, water = pd ch4 ----
            float air = p0.w * sc3 + mn3;
            float water = p1.x * sc4 + mn4;
            float hd = air - water;
            float hn = hd * hd;
            float hdd = air * air;
            if (s == 0) { hbn0 += hn; hbd0 += hdd; }
            else if (s == 1) { hbn1 += hn; hbd1 += hdd; }
            else if (s == 2) { hbn2 += hn; hbd2 += hdd; }
            else { hbn3 += hn; hbd3 += hdd; }

            // ---- frost (ch2): relu((prev - pred)*scale)  (mean cancels) ----
            float fr = fmaxf((pv2 - p0.z) * sc2, 0.f);
            // ---- pressure (ch0) ----
            float pg = fmaxf((pv0 - p0.x) * sc0, 0.f) * 0.5f;
            float rest = fr * fr + pg * pg;

            // ---- temp penalty: ch 5,7,8,9,11 ----
            float t5 = fmaxf(fabsf(p1.y - pv5) * sc5 - 5.f, 0.f);
            float t7 = fmaxf(fabsf(p1.w - pv7) * sc7 - 5.f, 0.f);
            float t8 = fmaxf(fabsf(p2.x - pv8) * sc8 - 5.f, 0.f);
            float t9 = fmaxf(fabsf(p2.y - pv9) * sc9 - 5.f, 0.f);
            float t11 = fmaxf(fabsf(p2.w - pv11) * sc11 - 5.f, 0.f);
            rest += 0.1f * (t5 * t5 + t7 * t7 + t8 * t8 + t9 * t9 + t11 * t11);

            acc_rest += sw * rest;

            // carry prev = this step's pred
            pv0 = p0.x; pv2 = p0.z; pv5 = p1.y; pv7 = p1.w;
            pv8 = p2.x; pv9 = p2.y; pv11 = p2.w;
        }
    }

    // ---- block reduction of 10 values ----
    float vals[10] = {acc_mse, acc_rest, hbn0, hbn1, hbn2, hbn3, hbd0, hbd1, hbd2, hbd3};
    __shared__ float red[4][10];
    const int lane = threadIdx.x & 63;
    const int wave = threadIdx.x >> 6;
#pragma unroll
    for (int i = 0; i < 10; ++i) {
        float v = vals[i];
#pragma unroll
        for (int off = 32; off; off >>= 1) v += __shfl_down(v, off, 64);
        if (lane == 0) red[wave][i] = v;
    }
    __syncthreads();
    if (threadIdx.x < 10) {
        float v = red[0][threadIdx.x] + red[1][threadIdx.x] +
                  red[2][threadIdx.x] + red[3][threadIdx.x];
        partials[threadIdx.x * NBLK + blockIdx.x] = v;
    }
}

__global__ __launch_bounds__(256) void loss_final(
    const float* __restrict__ partials,  // (10, NBLK)
    float* __restrict__ out)
{
    __shared__ float red[4];
    __shared__ float tot[10];
    const int t = threadIdx.x;
    const int lane = t & 63;
    const int wave = t >> 6;

    for (int c = 0; c < 10; ++c) {
        float v = 0.f;
        for (int i = t; i < NBLK; i += 256) v += partials[c * NBLK + i];
#pragma unroll
        for (int off = 32; off; off >>= 1) v += __shfl_down(v, off, 64);
        if (lane == 0) red[wave] = v;
        __syncthreads();
        if (t == 0) tot[c] = red[0] + red[1] + red[2] + red[3];
        __syncthreads();
    }

    if (t == 0) {
        const float stepw[4] = {0.48f, 0.24f, 0.16f, 0.12f};
        const float invB = 1.0f / (float)B_TOTAL;
        float mse = tot[0] * invB;
        float phys = tot[1] * invB;  // frost+press+temp, step-weighted already
#pragma unroll
        for (int s = 0; s < 4; ++s) {
            float num = tot[2 + s] * invB;
            float den = tot[6 + s] * invB + 1e-6f;
            phys += stepw[s] * (num / den);
        }
        out[0] = mse + 0.1f * phys;
    }
}

extern "C" void kernel_launch(void* const* d_in, const int* in_sizes, int n_in,
                              void* d_out, int out_size, void* d_ws, size_t ws_size,
                              hipStream_t stream) {
    const float* pred   = (const float*)d_in[0];
    const float* target = (const float*)d_in[1];
    const float* inseq  = (const float*)d_in[2];
    const float* scale  = (const float*)d_in[3];
    const float* mean   = (const float*)d_in[4];
    float* out = (float*)d_out;
    float* partials = (float*)d_ws;  // 10 * NBLK floats = 80 KB

    loss_partial<<<NBLK, NTHR, 0, stream>>>(pred, target, inseq, scale, mean, partials);
    loss_final<<<1, 256, 0, stream>>>(partials, out);
}

// Round 2
// 65.220 us; speedup vs baseline: 1.5618x; 1.5618x over previous
//
#include <hip/hip_runtime.h>

#define B_TOTAL 524288
#define TILE_B 128
#define NBLK (B_TOTAL / TILE_B)   // 4096
#define NTHR 256

// MSE weights after VAR_IDX mapping: ch0:0.15 ch1:0.15 ch2:0.5 ch3:0.1 ch4:0.1
// step_w = (1/(s+1)) / (25/12) = [0.48, 0.24, 0.16, 0.12]

__global__ __launch_bounds__(NTHR) void loss_partial(
    const float* __restrict__ pred,    // (B,4,16)
    const float* __restrict__ target,  // (B,4,16)
    const float* __restrict__ inseq,   // (B,8,16)
    const float* __restrict__ scale,   // (16)
    const float* __restrict__ mean,    // (16)
    float* __restrict__ partials)      // (10, NBLK) SoA
{
    // pred: 128 b * 16 float4, swizzled idx ^ ((idx>>4)&7)  (b = idx>>4 folded into bank bits)
    // target halves (ch0-7): 128 b * 8 float4, swizzled idx ^ ((idx>>3)&7)
    __shared__ float4 sp[TILE_B * 16];
    __shared__ float4 st[TILE_B * 8];
    __shared__ float red[4][10];

    const int tid = threadIdx.x;
    const size_t tile0 = (size_t)blockIdx.x * TILE_B;

    const float4* prg = reinterpret_cast<const float4*>(pred) + tile0 * 16;
    const float4* tgg = reinterpret_cast<const float4*>(target) + tile0 * 16;

    // ---- stage pred: 2048 float4, fully coalesced (1KB contiguous per wave instr) ----
#pragma unroll
    for (int i = 0; i < 8; ++i) {
        int j = i * NTHR + tid;
        sp[j ^ ((j >> 4) & 7)] = prg[j];
    }
    // ---- stage target first halves of each step row (ch0-7): 1024 float4 ----
#pragma unroll
    for (int i = 0; i < 4; ++i) {
        int j = i * NTHR + tid;                 // j = row*2 + half
        st[j ^ ((j >> 3) & 7)] = tgg[((j >> 1) << 2) | (j & 1)];
    }

    const int b = tid >> 1;        // 0..127
    const int shalf = tid & 1;     // 0: steps 0,1   1: steps 2,3

    // prev channels needed: 0,2,5,7,8,9,11
    float pv0 = 0.f, pv2 = 0.f, pv5 = 0.f, pv7 = 0.f, pv8 = 0.f, pv9 = 0.f, pv11 = 0.f;
    if (!shalf) {
        // inseq[b, 7, :]: byte offset (tile0+b)*512 + 448, 16B-aligned
        const float4* iq = reinterpret_cast<const float4*>(inseq + (tile0 + (size_t)b) * 128 + 112);
        float4 q0 = iq[0], q1 = iq[1], q2 = iq[2];
        pv0 = q0.x; pv2 = q0.z; pv5 = q1.y; pv7 = q1.w;
        pv8 = q2.x; pv9 = q2.y; pv11 = q2.w;
    }

    const float sc0 = scale[0], sc2 = scale[2], sc3 = scale[3], sc4 = scale[4];
    const float sc5 = scale[5], sc7 = scale[7], sc8 = scale[8], sc9 = scale[9], sc11 = scale[11];
    const float mn3 = mean[3], mn4 = mean[4];

    __syncthreads();

    auto ldp = [&](int s, int w) -> float4 {
        int i = (b << 4) + (s << 2) + w;
        return sp[i ^ ((i >> 4) & 7)];
    };
    auto ldt = [&](int s, int h) -> float4 {
        int i = (b << 3) + (s << 1) + h;
        return st[i ^ ((i >> 3) & 7)];
    };

    const int sA = shalf ? 2 : 0;
    if (shalf) {
        // prev for step 2 = pred row 1 (in LDS)
        float4 q0 = ldp(1, 0), q1 = ldp(1, 1), q2 = ldp(1, 2);
        pv0 = q0.x; pv2 = q0.z; pv5 = q1.y; pv7 = q1.w;
        pv8 = q2.x; pv9 = q2.y; pv11 = q2.w;
    }

    const float swA = shalf ? 0.16f : 0.48f;
    const float swB = shalf ? 0.12f : 0.24f;

    float acc_mse = 0.f, acc_rest = 0.f;
    float hnA, hdA, hnB, hdB;

    auto cell = [&](int s, float sw, float& hn, float& hd) {
        float4 p0 = ldp(s, 0), p1 = ldp(s, 1), p2 = ldp(s, 2);
        float4 t0 = ldt(s, 0), t1 = ldt(s, 1);
        // MSE ch0-4
        float d0 = p0.x - t0.x, d1 = p0.y - t0.y, d2 = p0.z - t0.z;
        float d3 = p0.w - t0.w, d4 = p1.x - t1.x;
        acc_mse += sw * (0.15f * d0 * d0 + 0.15f * d1 * d1 + 0.5f * d2 * d2 +
                         0.1f * d3 * d3 + 0.1f * d4 * d4);
        // heat balance (per-step mean ratio -> separate accumulators)
        float air = p0.w * sc3 + mn3;
        float water = p1.x * sc4 + mn4;
        float h = air - water;
        hn = h * h;
        hd = air * air;
        // frost (ch2) / pressure (ch0): mean cancels in pd-pv
        float fr = fmaxf((pv2 - p0.z) * sc2, 0.f);
        float pg = fmaxf((pv0 - p0.x) * sc0, 0.f) * 0.5f;
        float rest = fr * fr + pg * pg;
        // temp penalty ch 5,7,8,9,11
        float t5 = fmaxf(fabsf(p1.y - pv5) * sc5 - 5.f, 0.f);
        float t7 = fmaxf(fabsf(p1.w - pv7) * sc7 - 5.f, 0.f);
        float t8 = fmaxf(fabsf(p2.x - pv8) * sc8 - 5.f, 0.f);
        float t9 = fmaxf(fabsf(p2.y - pv9) * sc9 - 5.f, 0.f);
        float t11 = fmaxf(fabsf(p2.w - pv11) * sc11 - 5.f, 0.f);
        rest += 0.1f * (t5 * t5 + t7 * t7 + t8 * t8 + t9 * t9 + t11 * t11);
        acc_rest += sw * rest;
        // carry prev
        pv0 = p0.x; pv2 = p0.z; pv5 = p1.y; pv7 = p1.w;
        pv8 = p2.x; pv9 = p2.y; pv11 = p2.w;
    };

    cell(sA,     swA, hnA, hdA);
    cell(sA + 1, swB, hnB, hdB);

    // route per-step heat accumulators to fixed slots (compile-time selects)
    float vals[10];
    vals[0] = acc_mse;
    vals[1] = acc_rest;
    vals[2] = shalf ? 0.f : hnA;
    vals[3] = shalf ? 0.f : hnB;
    vals[4] = shalf ? hnA : 0.f;
    vals[5] = shalf ? hnB : 0.f;
    vals[6] = shalf ? 0.f : hdA;
    vals[7] = shalf ? 0.f : hdB;
    vals[8] = shalf ? hdA : 0.f;
    vals[9] = shalf ? hdB : 0.f;

    const int lane = tid & 63;
    const int wave = tid >> 6;
#pragma unroll
    for (int i = 0; i < 10; ++i) {
        float v = vals[i];
#pragma unroll
        for (int off = 32; off; off >>= 1) v += __shfl_down(v, off, 64);
        if (lane == 0) red[wave][i] = v;
    }
    __syncthreads();
    if (tid < 10) {
        partials[tid * NBLK + blockIdx.x] =
            red[0][tid] + red[1][tid] + red[2][tid] + red[3][tid];
    }
}

__global__ __launch_bounds__(640) void loss_final(
    const float* __restrict__ partials,  // (10, NBLK)
    float* __restrict__ out)
{
    __shared__ float tot[10];
    const int t = threadIdx.x;
    const int c = t >> 6;      // one wave per channel, 10 waves
    const int lane = t & 63;

    float v = 0.f;
#pragma unroll
    for (int i = 0; i < NBLK / 64; ++i)
        v += partials[(size_t)c * NBLK + i * 64 + lane];
#pragma unroll
    for (int off = 32; off; off >>= 1) v += __shfl_down(v, off, 64);
    if (lane == 0) tot[c] = v;
    __syncthreads();

    if (t == 0) {
        const float stepw[4] = {0.48f, 0.24f, 0.16f, 0.12f};
        const float invB = 1.0f / (float)B_TOTAL;
        float mse = tot[0] * invB;
        float phys = tot[1] * invB;
#pragma unroll
        for (int s = 0; s < 4; ++s) {
            float num = tot[2 + s] * invB;
            float den = tot[6 + s] * invB + 1e-6f;
            phys += stepw[s] * (num / den);
        }
        out[0] = mse + 0.1f * phys;
    }
}

extern "C" void kernel_launch(void* const* d_in, const int* in_sizes, int n_in,
                              void* d_out, int out_size, void* d_ws, size_t ws_size,
                              hipStream_t stream) {
    const float* pred   = (const float*)d_in[0];
    const float* target = (const float*)d_in[1];
    const float* inseq  = (const float*)d_in[2];
    const float* scale  = (const float*)d_in[3];
    const float* mean   = (const float*)d_in[4];
    float* out = (float*)d_out;
    float* partials = (float*)d_ws;  // 10 * NBLK floats = 160 KB

    loss_partial<<<NBLK, NTHR, 0, stream>>>(pred, target, inseq, scale, mean, partials);
    loss_final<<<1, 640, 0, stream>>>(partials, out);
}

// Round 3
// 62.205 us; speedup vs baseline: 1.6376x; 1.0485x over previous
//
#include <hip/hip_runtime.h>

#define B_TOTAL 524288
#define TILE_B 128
#define NBLK (B_TOTAL / TILE_B)   // 4096
#define NTHR 512

// MSE weights after VAR_IDX mapping: ch0:0.15 ch1:0.15 ch2:0.5 ch3:0.1 ch4:0.1
// step_w = (1/(s+1)) / (25/12) = [0.48, 0.24, 0.16, 0.12]
// One thread per (b, s): b = tid>>2, s = tid&3. prev = pred[s-1] from LDS (s>0)
// or inseq[b,7,:] direct (s==0). No carry chain -> no cross-step dependency.

__global__ __launch_bounds__(NTHR, 8) void loss_partial(
    const float* __restrict__ pred,    // (B,4,16)
    const float* __restrict__ target,  // (B,4,16)
    const float* __restrict__ inseq,   // (B,8,16)
    const float* __restrict__ scale,   // (16)
    const float* __restrict__ mean,    // (16)
    float* __restrict__ partials)      // (10, NBLK) SoA
{
    // sp: pred ch0-11 only, 128 rows*4steps*3 float4 = 1536 float4 = 24KB
    //     linear idx i = (b*4+s)*3 + w, stored/read at i ^ ((i>>3)&7)
    // st: target ch0-7, idx i = (b*4+s)*2 + h, swizzled same way = 16KB
    // reduction scratch aliases st (dead by then). Total LDS = 40KB -> 4 blocks/CU.
    __shared__ float4 sp[TILE_B * 12];
    __shared__ float4 st[TILE_B * 8];

    const int tid = threadIdx.x;
    const size_t tile0 = (size_t)blockIdx.x * TILE_B;

    const float4* prg = reinterpret_cast<const float4*>(pred) + tile0 * 16;
    const float4* tgg = reinterpret_cast<const float4*>(target) + tile0 * 16;

    // ---- stage pred ch0-11: 1536 float4, contiguous runs of 48B ----
#pragma unroll
    for (int it = 0; it < 3; ++it) {
        int j = it * NTHR + tid;           // 0..1535
        int row = j / 3, k = j - row * 3;  // row = b*4+s
        sp[j ^ ((j >> 3) & 7)] = prg[row * 4 + k];
    }
    // ---- stage target ch0-7: 1024 float4 ----
#pragma unroll
    for (int it = 0; it < 2; ++it) {
        int j = it * NTHR + tid;           // 0..1023, j = row*2 + half
        st[j ^ ((j >> 3) & 7)] = tgg[((j >> 1) << 2) | (j & 1)];
    }

    const int b = tid >> 2;
    const int s = tid & 3;

    // prev channels needed: 0,2,5,7,8,9,11
    float pv0 = 0.f, pv2 = 0.f, pv5 = 0.f, pv7 = 0.f, pv8 = 0.f, pv9 = 0.f, pv11 = 0.f;
    if (s == 0) {
        // inseq[b,7,0..11]: byte offset (tile0+b)*512 + 448, 16B aligned
        const float4* iq = reinterpret_cast<const float4*>(inseq + (tile0 + (size_t)b) * 128 + 112);
        float4 q0 = iq[0], q1 = iq[1], q2 = iq[2];
        pv0 = q0.x; pv2 = q0.z; pv5 = q1.y; pv7 = q1.w;
        pv8 = q2.x; pv9 = q2.y; pv11 = q2.w;
    }

    const float sc0 = scale[0], sc2 = scale[2], sc3 = scale[3], sc4 = scale[4];
    const float sc5 = scale[5], sc7 = scale[7], sc8 = scale[8], sc9 = scale[9], sc11 = scale[11];
    const float mn3 = mean[3], mn4 = mean[4];
    const float sw = (s == 0) ? 0.48f : (s == 1) ? 0.24f : (s == 2) ? 0.16f : 0.12f;

    __syncthreads();

    auto ldp = [&](int row, int w) -> float4 {
        int i = row * 3 + w;
        return sp[i ^ ((i >> 3) & 7)];
    };
    auto ldt = [&](int row, int h) -> float4 {
        int i = row * 2 + h;
        return st[i ^ ((i >> 3) & 7)];
    };

    const int row = b * 4 + s;
    if (s != 0) {
        float4 q0 = ldp(row - 1, 0), q1 = ldp(row - 1, 1), q2 = ldp(row - 1, 2);
        pv0 = q0.x; pv2 = q0.z; pv5 = q1.y; pv7 = q1.w;
        pv8 = q2.x; pv9 = q2.y; pv11 = q2.w;
    }

    float4 p0 = ldp(row, 0), p1 = ldp(row, 1), p2 = ldp(row, 2);
    float4 t0 = ldt(row, 0), t1 = ldt(row, 1);

    // ---- MSE ch0-4, step-weighted ----
    float d0 = p0.x - t0.x, d1 = p0.y - t0.y, d2 = p0.z - t0.z;
    float d3 = p0.w - t0.w, d4 = p1.x - t1.x;
    float acc_mse = sw * (0.15f * d0 * d0 + 0.15f * d1 * d1 + 0.5f * d2 * d2 +
                          0.1f * d3 * d3 + 0.1f * d4 * d4);

    // ---- heat balance (per-step ratio -> per-step sums) ----
    float air = p0.w * sc3 + mn3;
    float water = p1.x * sc4 + mn4;
    float hdf = air - water;
    float hn = hdf * hdf;
    float hd = air * air;

    // ---- frost (ch2) / pressure (ch0): mean cancels in pd-pv ----
    float fr = fmaxf((pv2 - p0.z) * sc2, 0.f);
    float pg = fmaxf((pv0 - p0.x) * sc0, 0.f) * 0.5f;
    float rest = fr * fr + pg * pg;
    // ---- temp penalty ch 5,7,8,9,11 ----
    float t5 = fmaxf(fabsf(p1.y - pv5) * sc5 - 5.f, 0.f);
    float t7 = fmaxf(fabsf(p1.w - pv7) * sc7 - 5.f, 0.f);
    float t8 = fmaxf(fabsf(p2.x - pv8) * sc8 - 5.f, 0.f);
    float t9 = fmaxf(fabsf(p2.y - pv9) * sc9 - 5.f, 0.f);
    float t11 = fmaxf(fabsf(p2.w - pv11) * sc11 - 5.f, 0.f);
    rest += 0.1f * (t5 * t5 + t7 * t7 + t8 * t8 + t9 * t9 + t11 * t11);
    float acc_rest = sw * rest;

    __syncthreads();   // st reads done; safe to reuse as reduction scratch

    // ---- reductions ----
    // full-wave reduce for mse/rest; s-group (lane&3) reduce for hn/hd
    const int lane = tid & 63;
    const int wave = tid >> 6;
#pragma unroll
    for (int off = 1; off < 64; off <<= 1) {
        acc_mse  += __shfl_xor(acc_mse, off, 64);
        acc_rest += __shfl_xor(acc_rest, off, 64);
    }
#pragma unroll
    for (int off = 4; off < 64; off <<= 1) {
        hn += __shfl_xor(hn, off, 64);
        hd += __shfl_xor(hd, off, 64);
    }

    float* red = reinterpret_cast<float*>(st);   // red[wave*10 + slot]
    if (lane == 0) { red[wave * 10 + 0] = acc_mse; red[wave * 10 + 1] = acc_rest; }
    if (lane < 4)  { red[wave * 10 + 2 + lane] = hn; red[wave * 10 + 6 + lane] = hd; }
    __syncthreads();

    if (tid < 10) {
        float v = 0.f;
#pragma unroll
        for (int w = 0; w < 8; ++w) v += red[w * 10 + tid];
        partials[tid * NBLK + blockIdx.x] = v;
    }
}

__global__ __launch_bounds__(640) void loss_final(
    const float* __restrict__ partials,  // (10, NBLK)
    float* __restrict__ out)
{
    __shared__ float tot[10];
    const int t = threadIdx.x;
    const int c = t >> 6;      // one wave per channel, 10 waves
    const int lane = t & 63;

    float v = 0.f;
#pragma unroll
    for (int i = 0; i < NBLK / 64; ++i)
        v += partials[(size_t)c * NBLK + i * 64 + lane];
#pragma unroll
    for (int off = 32; off; off >>= 1) v += __shfl_down(v, off, 64);
    if (lane == 0) tot[c] = v;
    __syncthreads();

    if (t == 0) {
        const float stepw[4] = {0.48f, 0.24f, 0.16f, 0.12f};
        const float invB = 1.0f / (float)B_TOTAL;
        float mse = tot[0] * invB;
        float phys = tot[1] * invB;
#pragma unroll
        for (int s = 0; s < 4; ++s) {
            float num = tot[2 + s] * invB;
            float den = tot[6 + s] * invB + 1e-6f;
            phys += stepw[s] * (num / den);
        }
        out[0] = mse + 0.1f * phys;
    }
}

extern "C" void kernel_launch(void* const* d_in, const int* in_sizes, int n_in,
                              void* d_out, int out_size, void* d_ws, size_t ws_size,
                              hipStream_t stream) {
    const float* pred   = (const float*)d_in[0];
    const float* target = (const float*)d_in[1];
    const float* inseq  = (const float*)d_in[2];
    const float* scale  = (const float*)d_in[3];
    const float* mean   = (const float*)d_in[4];
    float* out = (float*)d_out;
    float* partials = (float*)d_ws;  // 10 * NBLK floats = 160 KB

    loss_partial<<<NBLK, NTHR, 0, stream>>>(pred, target, inseq, scale, mean, partials);
    loss_final<<<1, 640, 0, stream>>>(partials, out);
}